// Round 1
// baseline (1725.040 us; speedup 1.0000x reference)
//
#include <hip/hip_runtime.h>

#define NITER   5
#define B_G     16
#define NPG     3125
#define EPG     50000
#define NNODES  50000
#define NEDGES  800000
#define FD      32
#define HD      64

#define TPB_E   256
#define BPG_E   196   // ceil(EPG/TPB_E)
#define TPB_N   64
#define BPG_N   49    // ceil(NPG/TPB_N)

// ---------------- CSR build (once per call; col is call-invariant) ----------------

__global__ __launch_bounds__(256) void count_kernel(const int* __restrict__ coli,
                                                    int* __restrict__ cnt)
{
    int e = blockIdx.x * 256 + threadIdx.x;
    if (e < NEDGES) atomicAdd(&cnt[coli[e]], 1);
}

__global__ __launch_bounds__(1024) void scan_kernel(const int* __restrict__ deg,
                                                    int* __restrict__ off, int n)
{
    __shared__ int buf[1024];
    __shared__ int carry_s;
    int tid = threadIdx.x;
    if (tid == 0) carry_s = 0;
    __syncthreads();
    for (int base = 0; base < n; base += 1024) {
        int idx = base + tid;
        int v = (idx < n) ? deg[idx] : 0;
        buf[tid] = v;
        __syncthreads();
        for (int o = 1; o < 1024; o <<= 1) {
            int t = (tid >= o) ? buf[tid - o] : 0;
            __syncthreads();
            buf[tid] += t;
            __syncthreads();
        }
        int incl = buf[tid];
        int carry = carry_s;
        if (idx < n) off[idx] = carry + incl - v;   // exclusive scan
        __syncthreads();
        if (tid == 1023) carry_s = carry + buf[1023];
        __syncthreads();
    }
    if (tid == 0) off[n] = carry_s;
}

__global__ __launch_bounds__(256) void fill_kernel(const int* __restrict__ coli,
                                                   const int* __restrict__ off,
                                                   int* __restrict__ cursor,
                                                   int* __restrict__ csr)
{
    int e = blockIdx.x * 256 + threadIdx.x;
    if (e < NEDGES) {
        int c = coli[e];
        int pos = atomicAdd(&cursor[c], 1);
        csr[off[c] + pos] = e;
    }
}

// ---------------- per-iteration kernels ----------------

// cu_e[g][j] = be1[j] + sum_k y[g][k]*We1[96+k][j]; cu_n likewise for node MLP.
// Also zeroes the per-graph aggregate accumulators for this iteration.
__global__ __launch_bounds__(1024) void prep_kernel(
    const float* __restrict__ y,
    const float* __restrict__ We1, const float* __restrict__ be1,
    const float* __restrict__ Wn1, const float* __restrict__ bn1,
    float* __restrict__ cu_e, float* __restrict__ cu_n,
    float* __restrict__ xagg, float* __restrict__ eagg)
{
    int tid = threadIdx.x;
    if (tid < B_G * FD) xagg[tid] = 0.0f;
    else                eagg[tid - B_G * FD] = 0.0f;

    int g = tid >> 6;
    int j = tid & 63;
    float ae = be1[j];
    float an = bn1[j];
    for (int k = 0; k < FD; ++k) {
        float yv = y[g * FD + k];
        ae = fmaf(yv, We1[(96 + k) * HD + j], ae);
        an = fmaf(yv, Wn1[(64 + k) * HD + j], an);
    }
    cu_e[g * HD + j] = ae;
    cu_n[g * HD + j] = an;
}

__global__ __launch_bounds__(TPB_E) void edge_kernel(
    const float* __restrict__ x,
    const float* __restrict__ ea_in,
    const int* __restrict__ rowi,
    const int* __restrict__ coli,
    const float* __restrict__ We1,
    const float* __restrict__ We2,
    const float* __restrict__ be2,
    const float* __restrict__ cu_e,
    float* __restrict__ ea_out)
{
    int g = blockIdx.x / BPG_E;
    int local = (blockIdx.x % BPG_E) * TPB_E + threadIdx.x;
    if (local >= EPG) return;
    long e = (long)g * EPG + local;
    int r = rowi[e];
    int c = coli[e];

    float h[HD];
    {
        const float4* cu4 = (const float4*)(cu_e + g * HD);
        #pragma unroll
        for (int q = 0; q < HD / 4; ++q) {
            float4 t = cu4[q];
            h[4*q+0] = t.x; h[4*q+1] = t.y; h[4*q+2] = t.z; h[4*q+3] = t.w;
        }
    }

    // layer 1: three 32-row segments [src | dst | e]; u-rows pre-folded into h.
#define SEG_L1(PTR, WBASE) { \
    const float4* p_ = (const float4*)(PTR); \
    const float* wb_ = (WBASE); \
    _Pragma("unroll 1") \
    for (int c4 = 0; c4 < 8; ++c4) { \
        float4 v = p_[c4]; \
        const float* wr_ = wb_ + c4 * 4 * HD; \
        _Pragma("unroll") \
        for (int j = 0; j < HD; ++j) h[j] = fmaf(v.x, wr_[j], h[j]); \
        _Pragma("unroll") \
        for (int j = 0; j < HD; ++j) h[j] = fmaf(v.y, wr_[HD + j], h[j]); \
        _Pragma("unroll") \
        for (int j = 0; j < HD; ++j) h[j] = fmaf(v.z, wr_[2*HD + j], h[j]); \
        _Pragma("unroll") \
        for (int j = 0; j < HD; ++j) h[j] = fmaf(v.w, wr_[3*HD + j], h[j]); \
    } }

    SEG_L1(x + (long)r * FD,  We1)
    SEG_L1(x + (long)c * FD,  We1 + 32 * HD)
    SEG_L1(ea_in + e * FD,    We1 + 64 * HD)
#undef SEG_L1

    float out[FD];
    {
        const float4* b4 = (const float4*)be2;
        #pragma unroll
        for (int q = 0; q < FD / 4; ++q) {
            float4 t = b4[q];
            out[4*q+0] = t.x; out[4*q+1] = t.y; out[4*q+2] = t.z; out[4*q+3] = t.w;
        }
    }
    #pragma unroll
    for (int k = 0; k < HD; ++k) {
        float hk = fmaxf(h[k], 0.0f);
        #pragma unroll
        for (int j = 0; j < FD; ++j)
            out[j] = fmaf(hk, We2[k * FD + j], out[j]);
    }

    float4* o4 = (float4*)(ea_out + e * FD);
    #pragma unroll
    for (int q = 0; q < FD / 4; ++q)
        o4[q] = make_float4(out[4*q], out[4*q+1], out[4*q+2], out[4*q+3]);
}

__global__ __launch_bounds__(TPB_N) void node_kernel(
    const float* __restrict__ x_in,
    const float* __restrict__ ea,
    const int* __restrict__ off,
    const int* __restrict__ csr,
    const float* __restrict__ Wn1,
    const float* __restrict__ Wn2,
    const float* __restrict__ bn2,
    const float* __restrict__ cu_n,
    float* __restrict__ x_out,
    float* __restrict__ xagg,
    float* __restrict__ eagg)
{
    __shared__ float sm[TPB_N][FD + 1];   // +1 pad: avoid 32-way bank conflict
    __shared__ float sdeg[TPB_N];
    int tid = threadIdx.x;
    int g = blockIdx.x / BPG_N;
    int local = (blockIdx.x % BPG_N) * TPB_N + tid;
    bool valid = local < NPG;
    int n = g * NPG + (valid ? local : 0);

    float es[FD];
    #pragma unroll
    for (int j = 0; j < FD; ++j) es[j] = 0.0f;
    int s0 = 0, s1 = 0;
    if (valid) { s0 = off[n]; s1 = off[n + 1]; }
    for (int i = s0; i < s1; ++i) {
        int eid = csr[i];
        const float4* p = (const float4*)(ea + (long)eid * FD);
        #pragma unroll
        for (int q = 0; q < FD / 4; ++q) {
            float4 v = p[q];
            es[4*q+0] += v.x; es[4*q+1] += v.y; es[4*q+2] += v.z; es[4*q+3] += v.w;
        }
    }
    int deg = s1 - s0;
    sdeg[tid] = (float)deg;
    float inv = 1.0f / (float)(deg > 1 ? deg : 1);
    #pragma unroll
    for (int j = 0; j < FD; ++j) sm[tid][j] = es[j] * inv;
    __syncthreads();

    // e_agg (raw sums): recover sums as mean*deg
    if (tid < FD) {
        float a = 0.0f;
        #pragma unroll 1
        for (int t = 0; t < TPB_N; ++t) a = fmaf(sm[t][tid], sdeg[t], a);
        atomicAdd(&eagg[g * FD + tid], a);
    }

    float h[HD];
    {
        const float4* cu4 = (const float4*)(cu_n + g * HD);
        #pragma unroll
        for (int q = 0; q < HD / 4; ++q) {
            float4 t = cu4[q];
            h[4*q+0] = t.x; h[4*q+1] = t.y; h[4*q+2] = t.z; h[4*q+3] = t.w;
        }
    }
    // seg 0: x[n]
    {
        const float4* p = (const float4*)(x_in + (long)n * FD);
        #pragma unroll 1
        for (int c4 = 0; c4 < 8; ++c4) {
            float4 v = p[c4];
            const float* wr = Wn1 + c4 * 4 * HD;
            #pragma unroll
            for (int j = 0; j < HD; ++j) h[j] = fmaf(v.x, wr[j], h[j]);
            #pragma unroll
            for (int j = 0; j < HD; ++j) h[j] = fmaf(v.y, wr[HD + j], h[j]);
            #pragma unroll
            for (int j = 0; j < HD; ++j) h[j] = fmaf(v.z, wr[2*HD + j], h[j]);
            #pragma unroll
            for (int j = 0; j < HD; ++j) h[j] = fmaf(v.w, wr[3*HD + j], h[j]);
        }
    }
    // seg 1: e_mean (from LDS; dynamic k index is fine there)
    {
        #pragma unroll 1
        for (int k = 0; k < FD; ++k) {
            float v = sm[tid][k];
            const float* wr = Wn1 + (FD + k) * HD;
            #pragma unroll
            for (int j = 0; j < HD; ++j) h[j] = fmaf(v, wr[j], h[j]);
        }
    }

    float out[FD];
    {
        const float4* b4 = (const float4*)bn2;
        #pragma unroll
        for (int q = 0; q < FD / 4; ++q) {
            float4 t = b4[q];
            out[4*q+0] = t.x; out[4*q+1] = t.y; out[4*q+2] = t.z; out[4*q+3] = t.w;
        }
    }
    #pragma unroll
    for (int k = 0; k < HD; ++k) {
        float hk = fmaxf(h[k], 0.0f);
        #pragma unroll
        for (int j = 0; j < FD; ++j)
            out[j] = fmaf(hk, Wn2[k * FD + j], out[j]);
    }

    if (valid) {
        float4* o4 = (float4*)(x_out + (long)n * FD);
        #pragma unroll
        for (int q = 0; q < FD / 4; ++q)
            o4[q] = make_float4(out[4*q], out[4*q+1], out[4*q+2], out[4*q+3]);
    }

    // x_agg reduce (reuse sm)
    __syncthreads();
    #pragma unroll
    for (int j = 0; j < FD; ++j) sm[tid][j] = valid ? out[j] : 0.0f;
    __syncthreads();
    if (tid < FD) {
        float a = 0.0f;
        #pragma unroll 1
        for (int t = 0; t < TPB_N; ++t) a += sm[t][tid];
        atomicAdd(&xagg[g * FD + tid], a);
    }
}

__global__ __launch_bounds__(1024) void global_kernel(
    const float* __restrict__ y_in,
    const float* __restrict__ xagg, const float* __restrict__ eagg,
    const float* __restrict__ Wg1, const float* __restrict__ bg1,
    const float* __restrict__ Wg2, const float* __restrict__ bg2,
    float* __restrict__ y_out)
{
    __shared__ float in_lds[B_G][100];     // stride 100: spreads banks
    __shared__ float h_lds[B_G][HD + 1];
    int tid = threadIdx.x;
    for (int idx = tid; idx < B_G * 96; idx += 1024) {
        int g2 = idx / 96, k = idx % 96;
        float v;
        if (k < 32)      v = xagg[g2 * 32 + k] * (1.0f / NPG);
        else if (k < 64) v = eagg[g2 * 32 + (k - 32)] * (1.0f / EPG);
        else             v = y_in[g2 * 32 + (k - 64)];
        in_lds[g2][k] = v;
    }
    __syncthreads();
    int g = tid >> 6, j = tid & 63;
    float h = bg1[j];
    for (int k = 0; k < 96; ++k)
        h = fmaf(in_lds[g][k], Wg1[k * HD + j], h);
    h_lds[g][j] = fmaxf(h, 0.0f);
    __syncthreads();
    if (j < FD) {
        float o = bg2[j];
        for (int k = 0; k < HD; ++k)
            o = fmaf(h_lds[g][k], Wg2[k * FD + j], o);
        y_out[g * FD + j] = o;
    }
}

// ---------------- launch ----------------

extern "C" void kernel_launch(void* const* d_in, const int* in_sizes, int n_in,
                              void* d_out, int out_size, void* d_ws, size_t ws_size,
                              hipStream_t stream)
{
    const float* x0  = (const float*)d_in[0];
    const float* ea0 = (const float*)d_in[1];
    const float* y0  = (const float*)d_in[2];
    const float* We1 = (const float*)d_in[3];
    const float* be1 = (const float*)d_in[4];
    const float* We2 = (const float*)d_in[5];
    const float* be2 = (const float*)d_in[6];
    const float* Wn1 = (const float*)d_in[7];
    const float* bn1 = (const float*)d_in[8];
    const float* Wn2 = (const float*)d_in[9];
    const float* bn2 = (const float*)d_in[10];
    const float* Wg1 = (const float*)d_in[11];
    const float* bg1 = (const float*)d_in[12];
    const float* Wg2 = (const float*)d_in[13];
    const float* bg2 = (const float*)d_in[14];
    const int*   ei  = (const int*)d_in[15];
    const int* rowi = ei;
    const int* coli = ei + NEDGES;

    float* out_x  = (float*)d_out;
    float* out_ea = out_x + (size_t)NNODES * FD;
    float* out_y  = out_ea + (size_t)NEDGES * FD;

    char* ws = (char*)d_ws;
    int*   off    = (int*)(ws + 0);          // 50001 ints
    int*   cursor = (int*)(ws + 200192);     // 50000 ints
    int*   csr    = (int*)(ws + 400384);     // 800000 ints
    float* xagg   = (float*)(ws + 3600384);  // 16*32
    float* eagg   = xagg + B_G * FD;         // 16*32
    float* cu_e   = (float*)(ws + 3604480);  // 16*64
    float* cu_n   = cu_e + B_G * HD;         // 16*64

    // CSR build (col fixed per call)
    hipMemsetAsync(cursor, 0, NNODES * sizeof(int), stream);
    count_kernel<<<(NEDGES + 255) / 256, 256, 0, stream>>>(coli, cursor);
    scan_kernel<<<1, 1024, 0, stream>>>(cursor, off, NNODES);
    hipMemsetAsync(cursor, 0, NNODES * sizeof(int), stream);
    fill_kernel<<<(NEDGES + 255) / 256, 256, 0, stream>>>(coli, off, cursor, csr);

    for (int it = 0; it < NITER; ++it) {
        const float* xc  = (it == 0) ? x0  : out_x;
        const float* eac = (it == 0) ? ea0 : out_ea;
        const float* yc  = (it == 0) ? y0  : out_y;

        prep_kernel<<<1, 1024, 0, stream>>>(yc, We1, be1, Wn1, bn1,
                                            cu_e, cu_n, xagg, eagg);
        edge_kernel<<<B_G * BPG_E, TPB_E, 0, stream>>>(xc, eac, rowi, coli,
                                                       We1, We2, be2, cu_e, out_ea);
        node_kernel<<<B_G * BPG_N, TPB_N, 0, stream>>>(xc, out_ea, off, csr,
                                                       Wn1, Wn2, bn2, cu_n,
                                                       out_x, xagg, eagg);
        global_kernel<<<1, 1024, 0, stream>>>(yc, xagg, eagg,
                                              Wg1, bg1, Wg2, bg2, out_y);
    }
}

// Round 2
// 947.338 us; speedup vs baseline: 1.8209x; 1.8209x over previous
//
#include <hip/hip_runtime.h>
#include <hip/hip_bf16.h>

#define NITER   5
#define B_G     16
#define NPG     3125
#define EPG     50000
#define NNODES  50000
#define NEDGES  800000
#define FD      32
#define HD      64

#define TPB_N   64
#define BPG_N   49    // ceil(NPG/TPB_N)

#define EDGE_TPG   391          // tiles of 128 edges per graph: ceil(50000/128)
#define EDGE_TILES (B_G * EDGE_TPG)
#define EDGE_BLOCKS 1024

typedef __attribute__((ext_vector_type(4))) float f32x4;
typedef __attribute__((ext_vector_type(8))) short bf16x8;

union FragU { bf16x8 v; unsigned int u[4]; };

__device__ inline unsigned short bf16_rn_u(float f) {
    unsigned int u = __float_as_uint(f);
    unsigned int r = (u + 0x7fffu + ((u >> 16) & 1u)) >> 16;
    return (unsigned short)r;
}
__device__ inline float bf16_up(unsigned short h) {
    return __uint_as_float(((unsigned int)h) << 16);
}
// split (a,b) into packed-bf16 hi word and lo word (elem order: a=low, b=high)
__device__ inline void split2(float a, float b, unsigned int& hi, unsigned int& lo) {
    __hip_bfloat162 h2 = __float22bfloat162_rn(make_float2(a, b));
    float2 hf = __bfloat1622float2(h2);
    __hip_bfloat162 l2 = __float22bfloat162_rn(make_float2(a - hf.x, b - hf.y));
    hi = *reinterpret_cast<unsigned int*>(&h2);
    lo = *reinterpret_cast<unsigned int*>(&l2);
}
__device__ inline unsigned int pack_hl(float v) {
    unsigned short h = bf16_rn_u(v);
    float lo = v - bf16_up(h);
    return (unsigned int)h | ((unsigned int)bf16_rn_u(lo) << 16);
}

// ---------------- CSR build (once per call; col is call-invariant) ----------------

__global__ __launch_bounds__(256) void count_kernel(const int* __restrict__ coli,
                                                    int* __restrict__ cnt)
{
    int e = blockIdx.x * 256 + threadIdx.x;
    if (e < NEDGES) atomicAdd(&cnt[coli[e]], 1);
}

__global__ __launch_bounds__(1024) void scan_kernel(const int* __restrict__ deg,
                                                    int* __restrict__ off, int n)
{
    __shared__ int buf[1024];
    __shared__ int carry_s;
    int tid = threadIdx.x;
    if (tid == 0) carry_s = 0;
    __syncthreads();
    for (int base = 0; base < n; base += 1024) {
        int idx = base + tid;
        int v = (idx < n) ? deg[idx] : 0;
        buf[tid] = v;
        __syncthreads();
        for (int o = 1; o < 1024; o <<= 1) {
            int t = (tid >= o) ? buf[tid - o] : 0;
            __syncthreads();
            buf[tid] += t;
            __syncthreads();
        }
        int incl = buf[tid];
        int carry = carry_s;
        if (idx < n) off[idx] = carry + incl - v;   // exclusive scan
        __syncthreads();
        if (tid == 1023) carry_s = carry + buf[1023];
        __syncthreads();
    }
    if (tid == 0) off[n] = carry_s;
}

__global__ __launch_bounds__(256) void fill_kernel(const int* __restrict__ coli,
                                                   const int* __restrict__ off,
                                                   int* __restrict__ cursor,
                                                   int* __restrict__ csr)
{
    int e = blockIdx.x * 256 + threadIdx.x;
    if (e < NEDGES) {
        int c = coli[e];
        int pos = atomicAdd(&cursor[c], 1);
        csr[off[c] + pos] = e;
    }
}

// ---------------- per-iteration kernels ----------------

__global__ __launch_bounds__(1024) void prep_kernel(
    const float* __restrict__ y,
    const float* __restrict__ We1, const float* __restrict__ be1,
    const float* __restrict__ Wn1, const float* __restrict__ bn1,
    float* __restrict__ cu_e, float* __restrict__ cu_n,
    float* __restrict__ xagg, float* __restrict__ eagg)
{
    int tid = threadIdx.x;
    if (tid < B_G * FD) xagg[tid] = 0.0f;
    else                eagg[tid - B_G * FD] = 0.0f;

    int g = tid >> 6;
    int j = tid & 63;
    float ae = be1[j];
    float an = bn1[j];
    for (int k = 0; k < FD; ++k) {
        float yv = y[g * FD + k];
        ae = fmaf(yv, We1[(96 + k) * HD + j], ae);
        an = fmaf(yv, Wn1[(64 + k) * HD + j], an);
    }
    cu_e[g * HD + j] = ae;
    cu_n[g * HD + j] = an;
}

// ---- MFMA edge kernel: per wave 32 edges (2 M-tiles of 16), N=64, split-bf16 ----
__global__ __launch_bounds__(256) void edge_mfma_kernel(
    const float* __restrict__ x,
    const float* __restrict__ ea_in,
    const int* __restrict__ rowi,
    const int* __restrict__ coli,
    const float* __restrict__ We1,   // [128][64] row-major
    const float* __restrict__ We2,   // [64][32]
    const float* __restrict__ be2,
    const float* __restrict__ cu_e,  // [16][64]
    float* __restrict__ ea_out)
{
    __shared__ unsigned int h_lds[4][32][68];  // per-wave h tile, stride 68 u32 (16B-aligned rows, ~2-way banks)

    const int tid = threadIdx.x;
    const int wid = tid >> 6;
    const int l   = tid & 63;
    const int lm  = l & 15;       // A/B row-col within 16-tile
    const int lg  = l >> 4;       // k-group (octet)
    const int koff = lg * 8;

    // ---- weight fragments in registers, hi/lo split (once per block) ----
    bf16x8 w1h[3][4], w1l[3][4];
    #pragma unroll
    for (int s = 0; s < 3; ++s) {
        #pragma unroll
        for (int n = 0; n < 4; ++n) {
            const float* base = We1 + (s * 32 + koff) * HD + n * 16 + lm;
            FragU fh, fl;
            #pragma unroll
            for (int p = 0; p < 4; ++p) {
                float a = base[(2 * p) * HD];
                float b = base[(2 * p + 1) * HD];
                split2(a, b, fh.u[p], fl.u[p]);
            }
            w1h[s][n] = fh.v;
            w1l[s][n] = fl.v;
        }
    }
    bf16x8 w2h[2][2], w2l[2][2];
    #pragma unroll
    for (int s = 0; s < 2; ++s) {
        #pragma unroll
        for (int n = 0; n < 2; ++n) {
            const float* base = We2 + (s * 32 + koff) * FD + n * 16 + lm;
            FragU fh, fl;
            #pragma unroll
            for (int p = 0; p < 4; ++p) {
                float a = base[(2 * p) * FD];
                float b = base[(2 * p + 1) * FD];
                split2(a, b, fh.u[p], fl.u[p]);
            }
            w2h[s][n] = fh.v;
            w2l[s][n] = fl.v;
        }
    }

    for (int tile = blockIdx.x; tile < EDGE_TILES; tile += gridDim.x) {
        int g  = tile / EDGE_TPG;
        int lt = tile - g * EDGE_TPG;
        long gbase = (long)g * EPG;
        long gend  = gbase + EPG;
        long e0    = gbase + (long)lt * 128 + (long)wid * 32;

        // gather per-edge inputs: lane lm = edge row, lg = k-octet
        int eidx[2], rr[2], cc[2];
        #pragma unroll
        for (int t = 0; t < 2; ++t) {
            long e = e0 + t * 16 + lm;
            if (e >= gend) e = gend - 1;
            eidx[t] = (int)e;
            rr[t] = rowi[eidx[t]];
            cc[t] = coli[eidx[t]];
        }
        f32x4 va[2][3][2];
        #pragma unroll
        for (int t = 0; t < 2; ++t) {
            const float* p0 = x     + (long)rr[t]   * FD + koff;
            const float* p1 = x     + (long)cc[t]   * FD + koff;
            const float* p2 = ea_in + (long)eidx[t] * FD + koff;
            va[t][0][0] = *(const f32x4*)p0; va[t][0][1] = *(const f32x4*)(p0 + 4);
            va[t][1][0] = *(const f32x4*)p1; va[t][1][1] = *(const f32x4*)(p1 + 4);
            va[t][2][0] = *(const f32x4*)p2; va[t][2][1] = *(const f32x4*)(p2 + 4);
        }

        // layer-1 accumulators: bias = cu_e (be1 + u-contribution), col = n*16+lm
        f32x4 acc1[2][4];
        #pragma unroll
        for (int n = 0; n < 4; ++n) {
            float b = cu_e[g * HD + n * 16 + lm];
            #pragma unroll
            for (int t = 0; t < 2; ++t) acc1[t][n] = (f32x4){b, b, b, b};
        }

        #pragma unroll
        for (int t = 0; t < 2; ++t) {
            #pragma unroll
            for (int s = 0; s < 3; ++s) {
                FragU ah, al;
                #pragma unroll
                for (int q = 0; q < 2; ++q) {
                    #pragma unroll
                    for (int p = 0; p < 2; ++p) {
                        split2(va[t][s][q][2 * p], va[t][s][q][2 * p + 1],
                               ah.u[q * 2 + p], al.u[q * 2 + p]);
                    }
                }
                #pragma unroll
                for (int n = 0; n < 4; ++n) {
                    acc1[t][n] = __builtin_amdgcn_mfma_f32_16x16x32_bf16(ah.v, w1h[s][n], acc1[t][n], 0, 0, 0);
                    acc1[t][n] = __builtin_amdgcn_mfma_f32_16x16x32_bf16(ah.v, w1l[s][n], acc1[t][n], 0, 0, 0);
                    acc1[t][n] = __builtin_amdgcn_mfma_f32_16x16x32_bf16(al.v, w1h[s][n], acc1[t][n], 0, 0, 0);
                }
            }
        }

        // relu + split + transpose via LDS (C rows = (lg*4+r), cols = n*16+lm)
        #pragma unroll
        for (int t = 0; t < 2; ++t) {
            #pragma unroll
            for (int n = 0; n < 4; ++n) {
                #pragma unroll
                for (int r = 0; r < 4; ++r) {
                    float v = fmaxf(acc1[t][n][r], 0.0f);
                    h_lds[wid][t * 16 + lg * 4 + r][n * 16 + lm] = pack_hl(v);
                }
            }
        }
        __builtin_amdgcn_s_waitcnt(0);  // lgkmcnt(0): own-wave LDS writes visible (no cross-wave sharing)

        // layer 2
        f32x4 acc2[2][2];
        #pragma unroll
        for (int n = 0; n < 2; ++n) {
            float b = be2[n * 16 + lm];
            #pragma unroll
            for (int t = 0; t < 2; ++t) acc2[t][n] = (f32x4){b, b, b, b};
        }
        #pragma unroll
        for (int t = 0; t < 2; ++t) {
            #pragma unroll
            for (int s = 0; s < 2; ++s) {
                const unsigned int* hp = &h_lds[wid][t * 16 + lm][s * 32 + koff];
                unsigned int u0 = hp[0], u1 = hp[1], u2 = hp[2], u3 = hp[3];
                unsigned int u4 = hp[4], u5 = hp[5], u6 = hp[6], u7 = hp[7];
                FragU ah, al;
                ah.u[0] = (u0 & 0xffffu) | (u1 << 16);
                ah.u[1] = (u2 & 0xffffu) | (u3 << 16);
                ah.u[2] = (u4 & 0xffffu) | (u5 << 16);
                ah.u[3] = (u6 & 0xffffu) | (u7 << 16);
                al.u[0] = (u0 >> 16) | (u1 & 0xffff0000u);
                al.u[1] = (u2 >> 16) | (u3 & 0xffff0000u);
                al.u[2] = (u4 >> 16) | (u5 & 0xffff0000u);
                al.u[3] = (u6 >> 16) | (u7 & 0xffff0000u);
                #pragma unroll
                for (int n = 0; n < 2; ++n) {
                    acc2[t][n] = __builtin_amdgcn_mfma_f32_16x16x32_bf16(ah.v, w2h[s][n], acc2[t][n], 0, 0, 0);
                    acc2[t][n] = __builtin_amdgcn_mfma_f32_16x16x32_bf16(ah.v, w2l[s][n], acc2[t][n], 0, 0, 0);
                    acc2[t][n] = __builtin_amdgcn_mfma_f32_16x16x32_bf16(al.v, w2h[s][n], acc2[t][n], 0, 0, 0);
                }
            }
        }

        // store: rows = lg*4+r, cols = n*16+lm
        #pragma unroll
        for (int t = 0; t < 2; ++t) {
            #pragma unroll
            for (int r = 0; r < 4; ++r) {
                long e = e0 + t * 16 + lg * 4 + r;
                if (e < gend) {
                    #pragma unroll
                    for (int n = 0; n < 2; ++n)
                        ea_out[e * FD + n * 16 + lm] = acc2[t][n][r];
                }
            }
        }
    }
}

__global__ __launch_bounds__(TPB_N) void node_kernel(
    const float* __restrict__ x_in,
    const float* __restrict__ ea,
    const int* __restrict__ off,
    const int* __restrict__ csr,
    const float* __restrict__ Wn1,
    const float* __restrict__ Wn2,
    const float* __restrict__ bn2,
    const float* __restrict__ cu_n,
    float* __restrict__ x_out,
    float* __restrict__ xagg,
    float* __restrict__ eagg)
{
    __shared__ float sm[TPB_N][FD + 1];
    __shared__ float sdeg[TPB_N];
    int tid = threadIdx.x;
    int g = blockIdx.x / BPG_N;
    int local = (blockIdx.x % BPG_N) * TPB_N + tid;
    bool valid = local < NPG;
    int n = g * NPG + (valid ? local : 0);

    float es[FD];
    #pragma unroll
    for (int j = 0; j < FD; ++j) es[j] = 0.0f;
    int s0 = 0, s1 = 0;
    if (valid) { s0 = off[n]; s1 = off[n + 1]; }
    for (int i = s0; i < s1; ++i) {
        int eid = csr[i];
        const float4* p = (const float4*)(ea + (long)eid * FD);
        #pragma unroll
        for (int q = 0; q < FD / 4; ++q) {
            float4 v = p[q];
            es[4*q+0] += v.x; es[4*q+1] += v.y; es[4*q+2] += v.z; es[4*q+3] += v.w;
        }
    }
    int deg = s1 - s0;
    sdeg[tid] = (float)deg;
    float inv = 1.0f / (float)(deg > 1 ? deg : 1);
    #pragma unroll
    for (int j = 0; j < FD; ++j) sm[tid][j] = es[j] * inv;
    __syncthreads();

    if (tid < FD) {
        float a = 0.0f;
        #pragma unroll 1
        for (int t = 0; t < TPB_N; ++t) a = fmaf(sm[t][tid], sdeg[t], a);
        atomicAdd(&eagg[g * FD + tid], a);
    }

    float h[HD];
    {
        const float4* cu4 = (const float4*)(cu_n + g * HD);
        #pragma unroll
        for (int q = 0; q < HD / 4; ++q) {
            float4 t = cu4[q];
            h[4*q+0] = t.x; h[4*q+1] = t.y; h[4*q+2] = t.z; h[4*q+3] = t.w;
        }
    }
    {
        const float4* p = (const float4*)(x_in + (long)n * FD);
        #pragma unroll 1
        for (int c4 = 0; c4 < 8; ++c4) {
            float4 v = p[c4];
            const float* wr = Wn1 + c4 * 4 * HD;
            #pragma unroll
            for (int j = 0; j < HD; ++j) h[j] = fmaf(v.x, wr[j], h[j]);
            #pragma unroll
            for (int j = 0; j < HD; ++j) h[j] = fmaf(v.y, wr[HD + j], h[j]);
            #pragma unroll
            for (int j = 0; j < HD; ++j) h[j] = fmaf(v.z, wr[2*HD + j], h[j]);
            #pragma unroll
            for (int j = 0; j < HD; ++j) h[j] = fmaf(v.w, wr[3*HD + j], h[j]);
        }
    }
    {
        #pragma unroll 1
        for (int k = 0; k < FD; ++k) {
            float v = sm[tid][k];
            const float* wr = Wn1 + (FD + k) * HD;
            #pragma unroll
            for (int j = 0; j < HD; ++j) h[j] = fmaf(v, wr[j], h[j]);
        }
    }

    float out[FD];
    {
        const float4* b4 = (const float4*)bn2;
        #pragma unroll
        for (int q = 0; q < FD / 4; ++q) {
            float4 t = b4[q];
            out[4*q+0] = t.x; out[4*q+1] = t.y; out[4*q+2] = t.z; out[4*q+3] = t.w;
        }
    }
    #pragma unroll
    for (int k = 0; k < HD; ++k) {
        float hk = fmaxf(h[k], 0.0f);
        #pragma unroll
        for (int j = 0; j < FD; ++j)
            out[j] = fmaf(hk, Wn2[k * FD + j], out[j]);
    }

    if (valid) {
        float4* o4 = (float4*)(x_out + (long)n * FD);
        #pragma unroll
        for (int q = 0; q < FD / 4; ++q)
            o4[q] = make_float4(out[4*q], out[4*q+1], out[4*q+2], out[4*q+3]);
    }

    __syncthreads();
    #pragma unroll
    for (int j = 0; j < FD; ++j) sm[tid][j] = valid ? out[j] : 0.0f;
    __syncthreads();
    if (tid < FD) {
        float a = 0.0f;
        #pragma unroll 1
        for (int t = 0; t < TPB_N; ++t) a += sm[t][tid];
        atomicAdd(&xagg[g * FD + tid], a);
    }
}

__global__ __launch_bounds__(1024) void global_kernel(
    const float* __restrict__ y_in,
    const float* __restrict__ xagg, const float* __restrict__ eagg,
    const float* __restrict__ Wg1, const float* __restrict__ bg1,
    const float* __restrict__ Wg2, const float* __restrict__ bg2,
    float* __restrict__ y_out)
{
    __shared__ float in_lds[B_G][100];
    __shared__ float h_lds[B_G][HD + 1];
    int tid = threadIdx.x;
    for (int idx = tid; idx < B_G * 96; idx += 1024) {
        int g2 = idx / 96, k = idx % 96;
        float v;
        if (k < 32)      v = xagg[g2 * 32 + k] * (1.0f / NPG);
        else if (k < 64) v = eagg[g2 * 32 + (k - 32)] * (1.0f / EPG);
        else             v = y_in[g2 * 32 + (k - 64)];
        in_lds[g2][k] = v;
    }
    __syncthreads();
    int g = tid >> 6, j = tid & 63;
    float h = bg1[j];
    for (int k = 0; k < 96; ++k)
        h = fmaf(in_lds[g][k], Wg1[k * HD + j], h);
    h_lds[g][j] = fmaxf(h, 0.0f);
    __syncthreads();
    if (j < FD) {
        float o = bg2[j];
        for (int k = 0; k < HD; ++k)
            o = fmaf(h_lds[g][k], Wg2[k * FD + j], o);
        y_out[g * FD + j] = o;
    }
}

// ---------------- launch ----------------

extern "C" void kernel_launch(void* const* d_in, const int* in_sizes, int n_in,
                              void* d_out, int out_size, void* d_ws, size_t ws_size,
                              hipStream_t stream)
{
    const float* x0  = (const float*)d_in[0];
    const float* ea0 = (const float*)d_in[1];
    const float* y0  = (const float*)d_in[2];
    const float* We1 = (const float*)d_in[3];
    const float* be1 = (const float*)d_in[4];
    const float* We2 = (const float*)d_in[5];
    const float* be2 = (const float*)d_in[6];
    const float* Wn1 = (const float*)d_in[7];
    const float* bn1 = (const float*)d_in[8];
    const float* Wn2 = (const float*)d_in[9];
    const float* bn2 = (const float*)d_in[10];
    const float* Wg1 = (const float*)d_in[11];
    const float* bg1 = (const float*)d_in[12];
    const float* Wg2 = (const float*)d_in[13];
    const float* bg2 = (const float*)d_in[14];
    const int*   ei  = (const int*)d_in[15];
    const int* rowi = ei;
    const int* coli = ei + NEDGES;

    float* out_x  = (float*)d_out;
    float* out_ea = out_x + (size_t)NNODES * FD;
    float* out_y  = out_ea + (size_t)NEDGES * FD;

    char* ws = (char*)d_ws;
    int*   off    = (int*)(ws + 0);          // 50001 ints
    int*   cursor = (int*)(ws + 200192);     // 50000 ints
    int*   csr    = (int*)(ws + 400384);     // 800000 ints
    float* xagg   = (float*)(ws + 3600384);  // 16*32
    float* eagg   = xagg + B_G * FD;         // 16*32
    float* cu_e   = (float*)(ws + 3604480);  // 16*64
    float* cu_n   = cu_e + B_G * HD;         // 16*64

    hipMemsetAsync(cursor, 0, NNODES * sizeof(int), stream);
    count_kernel<<<(NEDGES + 255) / 256, 256, 0, stream>>>(coli, cursor);
    scan_kernel<<<1, 1024, 0, stream>>>(cursor, off, NNODES);
    hipMemsetAsync(cursor, 0, NNODES * sizeof(int), stream);
    fill_kernel<<<(NEDGES + 255) / 256, 256, 0, stream>>>(coli, off, cursor, csr);

    for (int it = 0; it < NITER; ++it) {
        const float* xc  = (it == 0) ? x0  : out_x;
        const float* eac = (it == 0) ? ea0 : out_ea;
        const float* yc  = (it == 0) ? y0  : out_y;

        prep_kernel<<<1, 1024, 0, stream>>>(yc, We1, be1, Wn1, bn1,
                                            cu_e, cu_n, xagg, eagg);
        edge_mfma_kernel<<<EDGE_BLOCKS, 256, 0, stream>>>(xc, eac, rowi, coli,
                                                          We1, We2, be2, cu_e, out_ea);
        node_kernel<<<B_G * BPG_N, TPB_N, 0, stream>>>(xc, out_ea, off, csr,
                                                       Wn1, Wn2, bn2, cu_n,
                                                       out_x, xagg, eagg);
        global_kernel<<<1, 1024, 0, stream>>>(yc, xagg, eagg,
                                              Wg1, bg1, Wg2, bg2, out_y);
    }
}